// Round 12
// baseline (163.613 us; speedup 1.0000x reference)
//
#include <hip/hip_runtime.h>
#include <hip/hip_bf16.h>

#define NN   50000
#define NE   800000
#define NB   196   // ceil(NN/256)

typedef __attribute__((ext_vector_type(8))) short short8;
typedef __attribute__((ext_vector_type(4))) float f32x4;

static __device__ __forceinline__ ushort f2bf(float f) {
    union { float f; unsigned u; } v; v.f = f;
    unsigned r = v.u + 0x7fffu + ((v.u >> 16) & 1u);   // round-to-nearest-even
    return (ushort)(r >> 16);
}
static __device__ __forceinline__ float bf2f(ushort h) {
    union { unsigned u; float f; } v; v.u = ((unsigned)h) << 16;
    return v.f;
}

// ---------------- count (+rank) + x->bf16 + weight-image prep ----------------
// wbt0: [128 n][128 k] bf16, byte = (n*256+kc*2)^((n&7)<<4)
// wbt1: TWO half-images of [128 n][128 k]: half h at ushort-offset h*16384,
//       byte-in-half = (n*256+kk*2)^((n&7)<<4); h=0 <- Wl1, h=1 <- Wr1.
__global__ __launch_bounds__(256) void count_k(
    const int* __restrict__ dst, int* __restrict__ deg,
    int* __restrict__ rank,
    const float* __restrict__ x, ushort* __restrict__ xb,
    const float* __restrict__ Wl0, const float* __restrict__ Wr0,
    const float* __restrict__ Wl1, const float* __restrict__ Wr1,
    ushort* __restrict__ wbt0, ushort* __restrict__ wbt1)
{
    int gid = blockIdx.x * 256 + threadIdx.x;

    if (gid < 2048) {
        {   // dense0 image
            int c = gid;
            int n  = c >> 4;
            int kc = (c & 15) * 8;
            const float* wsrc = (kc < 64) ? (Wl0 + n * 64 + kc) : (Wr0 + n * 64 + (kc - 64));
            float4 f0 = *(const float4*)(wsrc);
            float4 f1 = *(const float4*)(wsrc + 4);
            short8 v;
            v[0] = f2bf(f0.x); v[1] = f2bf(f0.y); v[2] = f2bf(f0.z); v[3] = f2bf(f0.w);
            v[4] = f2bf(f1.x); v[5] = f2bf(f1.y); v[6] = f2bf(f1.z); v[7] = f2bf(f1.w);
            int byte = (n * 256 + kc * 2) ^ ((n & 7) << 4);
            *(short8*)((char*)wbt0 + byte) = v;
        }
        #pragma unroll
        for (int rep = 0; rep < 2; ++rep) {   // dense1 half-images
            int c = gid + rep * 2048;
            int n  = c >> 5;
            int kc = (c & 31) * 8;
            int h  = (kc >= 128);
            int kk = kc - h * 128;
            const float* wsrc = h ? (Wr1 + n * 128 + kk) : (Wl1 + n * 128 + kk);
            float4 f0 = *(const float4*)(wsrc);
            float4 f1 = *(const float4*)(wsrc + 4);
            short8 v;
            v[0] = f2bf(f0.x); v[1] = f2bf(f0.y); v[2] = f2bf(f0.z); v[3] = f2bf(f0.w);
            v[4] = f2bf(f1.x); v[5] = f2bf(f1.y); v[6] = f2bf(f1.z); v[7] = f2bf(f1.w);
            int byte = h * 32768 + ((n * 256 + kk * 2) ^ ((n & 7) << 4));
            *(short8*)((char*)wbt1 + byte) = v;
        }
    }

    int base = gid * 4;
    float4 f = *(const float4*)(x + base);
    ushort4 o;
    o.x = f2bf(f.x); o.y = f2bf(f.y); o.z = f2bf(f.z); o.w = f2bf(f.w);
    *(ushort4*)(xb + base) = o;

    int d = dst[gid];
    rank[gid] = atomicAdd(&deg[d], 1);
}

__global__ __launch_bounds__(256) void partial_k(
    const int* __restrict__ deg, int* __restrict__ bsum)
{
    int gid = blockIdx.x * 256 + threadIdx.x;
    int v = (gid < NN) ? deg[gid] : 0;
    #pragma unroll
    for (int off = 32; off > 0; off >>= 1) v += __shfl_xor(v, off, 64);
    __shared__ int wsum[4];
    if ((threadIdx.x & 63) == 0) wsum[threadIdx.x >> 6] = v;
    __syncthreads();
    if (threadIdx.x == 0)
        bsum[blockIdx.x] = wsum[0] + wsum[1] + wsum[2] + wsum[3];
}

__global__ __launch_bounds__(256) void emit_k(
    const int* __restrict__ deg, const int* __restrict__ bsum,
    int* __restrict__ rowptr)
{
    __shared__ int s[256], sb[256];
    int tid = threadIdx.x;
    int gid = blockIdx.x * 256 + tid;
    int v  = (gid < NN) ? deg[gid] : 0;
    int bv = (tid < NB) ? bsum[tid] : 0;
    s[tid] = v; sb[tid] = bv;
    __syncthreads();
    for (int off = 1; off < 256; off <<= 1) {
        int a1 = (tid >= off) ? s[tid - off] : 0;
        int a2 = (tid >= off) ? sb[tid - off] : 0;
        __syncthreads();
        s[tid] += a1; sb[tid] += a2;
        __syncthreads();
    }
    int boff = (blockIdx.x == 0) ? 0 : sb[blockIdx.x - 1];
    if (gid < NN) rowptr[gid] = boff + s[tid] - v;
    if (blockIdx.x == 0 && tid == 0) rowptr[NN] = NE;
}

__global__ __launch_bounds__(256) void fill_k(
    const int* __restrict__ src, const int* __restrict__ dst,
    const int* __restrict__ rowptr, const int* __restrict__ rank,
    int* __restrict__ nbr)
{
    int e = blockIdx.x * 256 + threadIdx.x;
    int d = dst[e];
    nbr[rowptr[d] + rank[e]] = src[e];
}

// ---------------- fused gather0+dense0 ----------------
// block = 64 rows. Gather: one node per 8-lane group x 2 rounds -> inA LDS.
// Then h0 = relu([agg0|x] @ [Wl0;Wr0]^T + bl0) via MFMA.
__global__ __launch_bounds__(256) void dense0_k(
    const ushort* __restrict__ xb, const int* __restrict__ rowptr,
    const int* __restrict__ nbr,
    const ushort* __restrict__ wbt0, const float* __restrict__ bl,
    ushort* __restrict__ h0)
{
    __shared__ ushort bt[128 * 128];   // 32 KB
    __shared__ ushort inA[64 * 64];    // 8 KB, swizzled
    __shared__ float  bl_s[128];

    #pragma unroll
    for (int c = 0; c < 8; ++c) {
        int i = threadIdx.x + c * 256;
        ((short8*)bt)[i] = ((const short8*)wbt0)[i];
    }
    if (threadIdx.x < 128) bl_s[threadIdx.x] = bl[threadIdx.x];

    int brow  = blockIdx.x * 64;
    int group = threadIdx.x >> 3;      // 0..31
    int sub   = threadIdx.x & 7;       // feature octet

    #pragma unroll
    for (int r = 0; r < 2; ++r) {
        int nl   = group * 2 + r;
        int node = brow + nl;
        if (node < NN) {
            int b = rowptr[node], e2 = rowptr[node + 1];
            float acc[8];
            #pragma unroll
            for (int j = 0; j < 8; ++j) acc[j] = 0.f;
            int e = b;
            for (; e + 4 <= e2; e += 4) {
                int s0 = nbr[e], s1 = nbr[e + 1], s2 = nbr[e + 2], s3 = nbr[e + 3];
                short8 v0 = *(const short8*)(xb + s0 * 64 + sub * 8);
                short8 v1 = *(const short8*)(xb + s1 * 64 + sub * 8);
                short8 v2 = *(const short8*)(xb + s2 * 64 + sub * 8);
                short8 v3 = *(const short8*)(xb + s3 * 64 + sub * 8);
                #pragma unroll
                for (int j = 0; j < 8; ++j)
                    acc[j] += (bf2f((ushort)v0[j]) + bf2f((ushort)v1[j]))
                            + (bf2f((ushort)v2[j]) + bf2f((ushort)v3[j]));
            }
            for (; e < e2; ++e) {
                int s = nbr[e];
                short8 v = *(const short8*)(xb + s * 64 + sub * 8);
                #pragma unroll
                for (int j = 0; j < 8; ++j) acc[j] += bf2f((ushort)v[j]);
            }
            float inv = 1.0f / fmaxf((float)(e2 - b), 1.0f);
            short8 o;
            #pragma unroll
            for (int j = 0; j < 8; ++j) o[j] = (short)f2bf(acc[j] * inv);
            int byte = (nl * 128 + sub * 16) ^ ((nl & 7) << 4);
            *(short8*)((char*)inA + byte) = o;
        }
    }
    __syncthreads();

    int w = threadIdx.x >> 6, l = threadIdx.x & 63;
    int l15 = l & 15, hi = l >> 4;
    int row  = w * 16 + l15;           // local row
    int grow = brow + row;
    int rowc = grow < NN ? grow : 0;

    short8 a[4];
    {
        int bA0 = (row * 128 + hi * 16) ^ ((l15 & 7) << 4);
        int bA1 = (row * 128 + 64 + hi * 16) ^ ((l15 & 7) << 4);
        a[0] = *(const short8*)((const char*)inA + bA0);
        a[1] = *(const short8*)((const char*)inA + bA1);
    }
    a[2] = *(const short8*)(xb + rowc * 64 + hi * 8);
    a[3] = *(const short8*)(xb + rowc * 64 + 32 + hi * 8);

    f32x4 acc[8];
    #pragma unroll
    for (int nt = 0; nt < 8; ++nt) acc[nt] = (f32x4){0.f, 0.f, 0.f, 0.f};

    #pragma unroll
    for (int ks = 0; ks < 4; ++ks) {
        #pragma unroll
        for (int nt = 0; nt < 8; ++nt) {
            int byte = ((nt * 16 + l15) * 256 + (ks * 32 + hi * 8) * 2) ^ ((l15 & 7) << 4);
            short8 bfr = *(const short8*)((const char*)bt + byte);
            acc[nt] = __builtin_amdgcn_mfma_f32_16x16x32_bf16(a[ks], bfr, acc[nt], 0, 0, 0);
        }
    }

    int rowbase = brow + w * 16 + hi * 4;
    #pragma unroll
    for (int r = 0; r < 4; ++r) {
        int ro = rowbase + r;
        if (ro < NN) {
            #pragma unroll
            for (int nt = 0; nt < 8; ++nt) {
                int col = nt * 16 + l15;
                float v = fmaxf(acc[nt][r] + bl_s[col], 0.f);
                h0[ro * 128 + col] = f2bf(v);
            }
        }
    }
}

// ---------------- fused gather1+dense1+fc ----------------
// block = 64 rows. Gather: one node per 16-lane group x 4 rounds -> inA LDS.
// bt staged in two 32KB k-halves. out = (relu([agg1|h0]@[Wl1;Wr1]^T+bl1))@Wfc^T+bfc
__global__ __launch_bounds__(256) void dense1_k(
    const ushort* __restrict__ h0, const int* __restrict__ rowptr,
    const int* __restrict__ nbr,
    const ushort* __restrict__ wbt1, const float* __restrict__ bl,
    const float* __restrict__ Wfc, const float* __restrict__ bfc,
    float* __restrict__ out)
{
    __shared__ ushort bt[128 * 128];   // 32 KB (one k-half at a time)
    __shared__ ushort inA[64 * 128];   // 16 KB, swizzled
    __shared__ float  bl_s[128];
    __shared__ float  wfc_s[256];

    #pragma unroll
    for (int c = 0; c < 8; ++c) {      // stage k-half 0
        int i = threadIdx.x + c * 256;
        ((short8*)bt)[i] = ((const short8*)wbt1)[i];
    }
    if (threadIdx.x < 128) bl_s[threadIdx.x] = bl[threadIdx.x];
    if (threadIdx.x < 256) wfc_s[threadIdx.x] = Wfc[threadIdx.x];

    int brow  = blockIdx.x * 64;
    int group = threadIdx.x >> 4;      // 0..15
    int sub   = threadIdx.x & 15;      // feature octet

    #pragma unroll
    for (int r = 0; r < 4; ++r) {
        int nl   = group * 4 + r;
        int node = brow + nl;
        if (node < NN) {
            int b = rowptr[node], e2 = rowptr[node + 1];
            float acc[8];
            #pragma unroll
            for (int j = 0; j < 8; ++j) acc[j] = 0.f;
            int e = b;
            for (; e + 4 <= e2; e += 4) {
                int s0 = nbr[e], s1 = nbr[e + 1], s2 = nbr[e + 2], s3 = nbr[e + 3];
                short8 v0 = *(const short8*)(h0 + s0 * 128 + sub * 8);
                short8 v1 = *(const short8*)(h0 + s1 * 128 + sub * 8);
                short8 v2 = *(const short8*)(h0 + s2 * 128 + sub * 8);
                short8 v3 = *(const short8*)(h0 + s3 * 128 + sub * 8);
                #pragma unroll
                for (int j = 0; j < 8; ++j)
                    acc[j] += (bf2f((ushort)v0[j]) + bf2f((ushort)v1[j]))
                            + (bf2f((ushort)v2[j]) + bf2f((ushort)v3[j]));
            }
            for (; e < e2; ++e) {
                int s = nbr[e];
                short8 v = *(const short8*)(h0 + s * 128 + sub * 8);
                #pragma unroll
                for (int j = 0; j < 8; ++j) acc[j] += bf2f((ushort)v[j]);
            }
            float inv = 1.0f / fmaxf((float)(e2 - b), 1.0f);
            short8 o;
            #pragma unroll
            for (int j = 0; j < 8; ++j) o[j] = (short)f2bf(acc[j] * inv);
            int byte = (nl * 256 + sub * 16) ^ ((nl & 7) << 4);
            *(short8*)((char*)inA + byte) = o;
        }
    }
    __syncthreads();

    int w = threadIdx.x >> 6, l = threadIdx.x & 63;
    int l15 = l & 15, hi = l >> 4;
    int row  = w * 16 + l15;
    int grow = brow + row;
    int rowc = grow < NN ? grow : 0;

    short8 a[8];
    #pragma unroll
    for (int ks = 0; ks < 4; ++ks) {   // agg1 from LDS
        int byte = (row * 256 + ks * 64 + hi * 16) ^ ((l15 & 7) << 4);
        a[ks] = *(const short8*)((const char*)inA + byte);
    }
    #pragma unroll
    for (int ks = 0; ks < 4; ++ks)     // own h0 row from global
        a[4 + ks] = *(const short8*)(h0 + rowc * 128 + ks * 32 + hi * 8);

    f32x4 acc[8];
    #pragma unroll
    for (int nt = 0; nt < 8; ++nt) acc[nt] = (f32x4){0.f, 0.f, 0.f, 0.f};

    #pragma unroll
    for (int ks = 0; ks < 4; ++ks) {   // k-half 0 (agg1 x Wl1)
        #pragma unroll
        for (int nt = 0; nt < 8; ++nt) {
            int byte = ((nt * 16 + l15) * 256 + (ks * 32 + hi * 8) * 2) ^ ((l15 & 7) << 4);
            short8 bfr = *(const short8*)((const char*)bt + byte);
            acc[nt] = __builtin_amdgcn_mfma_f32_16x16x32_bf16(a[ks], bfr, acc[nt], 0, 0, 0);
        }
    }
    __syncthreads();
    #pragma unroll
    for (int c = 0; c < 8; ++c) {      // stage k-half 1
        int i = threadIdx.x + c * 256;
        ((short8*)bt)[i] = ((const short8*)(wbt1 + 16384))[i];
    }
    __syncthreads();
    #pragma unroll
    for (int ks = 0; ks < 4; ++ks) {   // k-half 1 (h0 x Wr1)
        #pragma unroll
        for (int nt = 0; nt < 8; ++nt) {
            int byte = ((nt * 16 + l15) * 256 + (ks * 32 + hi * 8) * 2) ^ ((l15 & 7) << 4);
            short8 bfr = *(const short8*)((const char*)bt + byte);
            acc[nt] = __builtin_amdgcn_mfma_f32_16x16x32_bf16(a[4 + ks], bfr, acc[nt], 0, 0, 0);
        }
    }

    int rowbase = brow + w * 16 + hi * 4;
    #pragma unroll
    for (int r = 0; r < 4; ++r) {
        float p0 = 0.f, p1 = 0.f;
        #pragma unroll
        for (int nt = 0; nt < 8; ++nt) {
            int col = nt * 16 + l15;
            float h1 = fmaxf(acc[nt][r] + bl_s[col], 0.f);
            p0 += h1 * wfc_s[col];
            p1 += h1 * wfc_s[128 + col];
        }
        p0 += __shfl_xor(p0, 1, 64); p0 += __shfl_xor(p0, 2, 64);
        p0 += __shfl_xor(p0, 4, 64); p0 += __shfl_xor(p0, 8, 64);
        p1 += __shfl_xor(p1, 1, 64); p1 += __shfl_xor(p1, 2, 64);
        p1 += __shfl_xor(p1, 4, 64); p1 += __shfl_xor(p1, 8, 64);
        int ro = rowbase + r;
        if (l15 == 0 && ro < NN) {
            float2 o; o.x = p0 + bfc[0]; o.y = p1 + bfc[1];
            *(float2*)(out + ro * 2) = o;
        }
    }
}

extern "C" void kernel_launch(void* const* d_in, const int* in_sizes, int n_in,
                              void* d_out, int out_size, void* d_ws, size_t ws_size,
                              hipStream_t stream)
{
    const float* x   = (const float*)d_in[0];
    const int*   ei  = (const int*)d_in[1];
    const float* Wl0 = (const float*)d_in[2];
    const float* bl0 = (const float*)d_in[3];
    const float* Wr0 = (const float*)d_in[4];
    const float* Wl1 = (const float*)d_in[5];
    const float* bl1 = (const float*)d_in[6];
    const float* Wr1 = (const float*)d_in[7];
    const float* Wfc = (const float*)d_in[8];
    const float* bfc = (const float*)d_in[9];
    float* out = (float*)d_out;

    const int* src = ei;
    const int* dst = ei + NE;

    // ws layout (bytes):
    //   deg    @ 0          (200,000)   <- memset
    //   rowptr @ 200,000    (200,004)
    //   rank   @ 400,004    (3,200,000)
    //   nbr    @ 3,600,004  (3,200,000)
    //   h0B    @ 19,600,016 (12,800,000)
    //   bsum   @ 32,400,016 (784)
    //   xb     @ 32,401,600 (6,400,000)
    //   wbt0   @ 38,801,600 (32,768)
    //   wbt1   @ 38,834,368 (65,536)
    char*   ws     = (char*)d_ws;
    int*    deg    = (int*)(ws);
    int*    rowptr = (int*)(ws + 200000);
    int*    rank   = (int*)(ws + 400004);
    int*    nbr    = (int*)(ws + 3600004);
    ushort* h0B    = (ushort*)(ws + 19600016);
    int*    bsum   = (int*)(ws + 32400016);
    ushort* xb     = (ushort*)(ws + 32401600);
    ushort* wbt0   = (ushort*)(ws + 38801600);
    ushort* wbt1   = (ushort*)(ws + 38834368);

    hipMemsetAsync(deg, 0, 200000, stream);

    count_k  <<<3125, 256, 0, stream>>>(dst, deg, rank, x, xb,
                                        Wl0, Wr0, Wl1, Wr1, wbt0, wbt1);
    partial_k<<<NB, 256, 0, stream>>>(deg, bsum);
    emit_k   <<<NB, 256, 0, stream>>>(deg, bsum, rowptr);
    fill_k   <<<3125, 256, 0, stream>>>(src, dst, rowptr, rank, nbr);

    dense0_k <<<782, 256, 0, stream>>>(xb, rowptr, nbr, wbt0, bl0, h0B);
    dense1_k <<<782, 256, 0, stream>>>(h0B, rowptr, nbr, wbt1, bl1, Wfc, bfc, out);
}

// Round 13
// 128.700 us; speedup vs baseline: 1.2713x; 1.2713x over previous
//
#include <hip/hip_runtime.h>
#include <hip/hip_bf16.h>

#define NN   50000
#define NE   800000
#define NB   196   // ceil(NN/256)

typedef __attribute__((ext_vector_type(8))) short short8;
typedef __attribute__((ext_vector_type(4))) float f32x4;
typedef __attribute__((ext_vector_type(2))) float f32x2;

static __device__ __forceinline__ ushort f2bf(float f) {
    union { float f; unsigned u; } v; v.f = f;
    unsigned r = v.u + 0x7fffu + ((v.u >> 16) & 1u);   // round-to-nearest-even
    return (ushort)(r >> 16);
}
static __device__ __forceinline__ float bf2f(ushort h) {
    union { unsigned u; float f; } v; v.u = ((unsigned)h) << 16;
    return v.f;
}

// ---------------- count (+rank) + x->bf16 + weight-image prep ----------------
__global__ __launch_bounds__(256) void count_k(
    const int* __restrict__ dst, int* __restrict__ deg,
    int* __restrict__ rank,
    const float* __restrict__ x, ushort* __restrict__ xb,
    const float* __restrict__ Wl0, const float* __restrict__ Wr0,
    const float* __restrict__ Wl1, const float* __restrict__ Wr1,
    ushort* __restrict__ wbt0, ushort* __restrict__ wbt1)
{
    int gid = blockIdx.x * 256 + threadIdx.x;

    if (gid < 2048) {
        {   // dense0 image
            int c = gid;
            int n  = c >> 4;
            int kc = (c & 15) * 8;
            const float* wsrc = (kc < 64) ? (Wl0 + n * 64 + kc) : (Wr0 + n * 64 + (kc - 64));
            float4 f0 = *(const float4*)(wsrc);
            float4 f1 = *(const float4*)(wsrc + 4);
            short8 v;
            v[0] = f2bf(f0.x); v[1] = f2bf(f0.y); v[2] = f2bf(f0.z); v[3] = f2bf(f0.w);
            v[4] = f2bf(f1.x); v[5] = f2bf(f1.y); v[6] = f2bf(f1.z); v[7] = f2bf(f1.w);
            int byte = (n * 256 + kc * 2) ^ ((n & 7) << 4);
            *(short8*)((char*)wbt0 + byte) = v;
        }
        #pragma unroll
        for (int rep = 0; rep < 2; ++rep) {   // dense1 image (single 64KB image)
            int c = gid + rep * 2048;
            int n  = c >> 5;
            int kc = (c & 31) * 8;
            const float* wsrc = (kc < 128) ? (Wl1 + n * 128 + kc) : (Wr1 + n * 128 + (kc - 128));
            float4 f0 = *(const float4*)(wsrc);
            float4 f1 = *(const float4*)(wsrc + 4);
            short8 v;
            v[0] = f2bf(f0.x); v[1] = f2bf(f0.y); v[2] = f2bf(f0.z); v[3] = f2bf(f0.w);
            v[4] = f2bf(f1.x); v[5] = f2bf(f1.y); v[6] = f2bf(f1.z); v[7] = f2bf(f1.w);
            int byte = (n * 512 + kc * 2) ^ ((n & 7) << 4);
            *(short8*)((char*)wbt1 + byte) = v;
        }
    }

    int base = gid * 4;
    float4 f = *(const float4*)(x + base);
    ushort4 o;
    o.x = f2bf(f.x); o.y = f2bf(f.y); o.z = f2bf(f.z); o.w = f2bf(f.w);
    *(ushort4*)(xb + base) = o;

    int d = dst[gid];
    rank[gid] = atomicAdd(&deg[d], 1);
}

__global__ __launch_bounds__(256) void partial_k(
    const int* __restrict__ deg, int* __restrict__ bsum)
{
    int gid = blockIdx.x * 256 + threadIdx.x;
    int v = (gid < NN) ? deg[gid] : 0;
    #pragma unroll
    for (int off = 32; off > 0; off >>= 1) v += __shfl_xor(v, off, 64);
    __shared__ int wsum[4];
    if ((threadIdx.x & 63) == 0) wsum[threadIdx.x >> 6] = v;
    __syncthreads();
    if (threadIdx.x == 0)
        bsum[blockIdx.x] = wsum[0] + wsum[1] + wsum[2] + wsum[3];
}

__global__ __launch_bounds__(256) void emit_k(
    const int* __restrict__ deg, const int* __restrict__ bsum,
    int* __restrict__ rowptr)
{
    __shared__ int s[256], sb[256];
    int tid = threadIdx.x;
    int gid = blockIdx.x * 256 + tid;
    int v  = (gid < NN) ? deg[gid] : 0;
    int bv = (tid < NB) ? bsum[tid] : 0;
    s[tid] = v; sb[tid] = bv;
    __syncthreads();
    for (int off = 1; off < 256; off <<= 1) {
        int a1 = (tid >= off) ? s[tid - off] : 0;
        int a2 = (tid >= off) ? sb[tid - off] : 0;
        __syncthreads();
        s[tid] += a1; sb[tid] += a2;
        __syncthreads();
    }
    int boff = (blockIdx.x == 0) ? 0 : sb[blockIdx.x - 1];
    if (gid < NN) rowptr[gid] = boff + s[tid] - v;
    if (blockIdx.x == 0 && tid == 0) rowptr[NN] = NE;
}

__global__ __launch_bounds__(256) void fill_k(
    const int* __restrict__ src, const int* __restrict__ dst,
    const int* __restrict__ rowptr, const int* __restrict__ rank,
    int* __restrict__ nbr)
{
    int e = blockIdx.x * 256 + threadIdx.x;
    int d = dst[e];
    nbr[rowptr[d] + rank[e]] = src[e];
}

// ---------------- gather0: one node per 8-lane group, 4-deep MLP ----------------
__global__ __launch_bounds__(256) void gather0_k(
    const ushort* __restrict__ xb, const int* __restrict__ rowptr,
    const int* __restrict__ nbr, ushort* __restrict__ agg0)
{
    int node = (blockIdx.x * 256 + threadIdx.x) >> 3;
    int sub  = threadIdx.x & 7;          // feature octet 0..7
    if (node >= NN) return;
    int b = rowptr[node], e2 = rowptr[node + 1];
    float acc[8];
    #pragma unroll
    for (int j = 0; j < 8; ++j) acc[j] = 0.f;

    int e = b;
    for (; e + 4 <= e2; e += 4) {
        int s0 = nbr[e], s1 = nbr[e + 1], s2 = nbr[e + 2], s3 = nbr[e + 3];
        short8 v0 = *(const short8*)(xb + s0 * 64 + sub * 8);
        short8 v1 = *(const short8*)(xb + s1 * 64 + sub * 8);
        short8 v2 = *(const short8*)(xb + s2 * 64 + sub * 8);
        short8 v3 = *(const short8*)(xb + s3 * 64 + sub * 8);
        #pragma unroll
        for (int j = 0; j < 8; ++j)
            acc[j] += (bf2f((ushort)v0[j]) + bf2f((ushort)v1[j]))
                    + (bf2f((ushort)v2[j]) + bf2f((ushort)v3[j]));
    }
    for (; e < e2; ++e) {
        int s = nbr[e];
        short8 v = *(const short8*)(xb + s * 64 + sub * 8);
        #pragma unroll
        for (int j = 0; j < 8; ++j) acc[j] += bf2f((ushort)v[j]);
    }

    float inv = 1.0f / fmaxf((float)(e2 - b), 1.0f);
    short8 o;
    #pragma unroll
    for (int j = 0; j < 8; ++j) o[j] = (short)f2bf(acc[j] * inv);
    *(short8*)(agg0 + node * 64 + sub * 8) = o;
}

// ---------------- gather1: fp8 h8 input (permuted rows), one node per 16-lane group ----------------
// h8 row layout: byte p = (col&15)*8 + (col>>4). Lane sub loads bytes [sub*8, sub*8+8)
// = cols {j*16+sub, j=0..7}. Decode with hardware cvt_pk_f32_fp8.
__global__ __launch_bounds__(256) void gather1_k(
    const unsigned char* __restrict__ h8, const int* __restrict__ rowptr,
    const int* __restrict__ nbr, ushort* __restrict__ agg1)
{
    int node = (blockIdx.x * 256 + threadIdx.x) >> 4;
    int sub  = threadIdx.x & 15;
    if (node >= NN) return;
    int b = rowptr[node], e2 = rowptr[node + 1];
    float acc[8];
    #pragma unroll
    for (int j = 0; j < 8; ++j) acc[j] = 0.f;

    int e = b;
    for (; e + 4 <= e2; e += 4) {
        int s0 = nbr[e], s1 = nbr[e + 1], s2 = nbr[e + 2], s3 = nbr[e + 3];
        uint2 w0 = *(const uint2*)(h8 + s0 * 128 + sub * 8);
        uint2 w1 = *(const uint2*)(h8 + s1 * 128 + sub * 8);
        uint2 w2 = *(const uint2*)(h8 + s2 * 128 + sub * 8);
        uint2 w3 = *(const uint2*)(h8 + s3 * 128 + sub * 8);
        #pragma unroll
        for (int q = 0; q < 4; ++q) {
            uint2 w = (q == 0) ? w0 : (q == 1) ? w1 : (q == 2) ? w2 : w3;
            f32x2 f01 = __builtin_amdgcn_cvt_pk_f32_fp8(w.x, false);
            f32x2 f23 = __builtin_amdgcn_cvt_pk_f32_fp8(w.x, true);
            f32x2 f45 = __builtin_amdgcn_cvt_pk_f32_fp8(w.y, false);
            f32x2 f67 = __builtin_amdgcn_cvt_pk_f32_fp8(w.y, true);
            acc[0] += f01[0]; acc[1] += f01[1];
            acc[2] += f23[0]; acc[3] += f23[1];
            acc[4] += f45[0]; acc[5] += f45[1];
            acc[6] += f67[0]; acc[7] += f67[1];
        }
    }
    for (; e < e2; ++e) {
        int s = nbr[e];
        uint2 w = *(const uint2*)(h8 + s * 128 + sub * 8);
        f32x2 f01 = __builtin_amdgcn_cvt_pk_f32_fp8(w.x, false);
        f32x2 f23 = __builtin_amdgcn_cvt_pk_f32_fp8(w.x, true);
        f32x2 f45 = __builtin_amdgcn_cvt_pk_f32_fp8(w.y, false);
        f32x2 f67 = __builtin_amdgcn_cvt_pk_f32_fp8(w.y, true);
        acc[0] += f01[0]; acc[1] += f01[1];
        acc[2] += f23[0]; acc[3] += f23[1];
        acc[4] += f45[0]; acc[5] += f45[1];
        acc[6] += f67[0]; acc[7] += f67[1];
    }

    float inv = 1.0f / fmaxf((float)(e2 - b), 1.0f);
    // agg1 in NORMAL layout: col = j*16 + sub. Per-j 16-lane stores are 32B-coalesced.
    #pragma unroll
    for (int j = 0; j < 8; ++j)
        agg1[node * 128 + j * 16 + sub] = f2bf(acc[j] * inv);
}

// ---------------- dense0: h0 = relu([agg0|x] @ [Wl0;Wr0]^T + bl0), MFMA ----------------
// Also emits fp8 copy h8 (permuted row layout) for gather1.
__global__ __launch_bounds__(256) void dense0_k(
    const ushort* __restrict__ xb, const ushort* __restrict__ agg0,
    const ushort* __restrict__ wbt0, const float* __restrict__ bl,
    ushort* __restrict__ h0, unsigned char* __restrict__ h8)
{
    __shared__ ushort bt[128 * 128];
    __shared__ float  bl_s[128];

    #pragma unroll
    for (int c = 0; c < 8; ++c) {
        int i = threadIdx.x + c * 256;
        ((short8*)bt)[i] = ((const short8*)wbt0)[i];
    }
    if (threadIdx.x < 128) bl_s[threadIdx.x] = bl[threadIdx.x];
    __syncthreads();

    int w = threadIdx.x >> 6, l = threadIdx.x & 63;
    int l15 = l & 15, hi = l >> 4;
    int row  = blockIdx.x * 64 + w * 16 + l15;
    int rowc = row < NN ? row : 0;

    short8 a[4];
    a[0] = *(const short8*)(agg0 + rowc * 64 + hi * 8);
    a[1] = *(const short8*)(agg0 + rowc * 64 + 32 + hi * 8);
    a[2] = *(const short8*)(xb + rowc * 64 + hi * 8);
    a[3] = *(const short8*)(xb + rowc * 64 + 32 + hi * 8);

    f32x4 acc[8];
    #pragma unroll
    for (int nt = 0; nt < 8; ++nt) acc[nt] = (f32x4){0.f, 0.f, 0.f, 0.f};

    #pragma unroll
    for (int ks = 0; ks < 4; ++ks) {
        #pragma unroll
        for (int nt = 0; nt < 8; ++nt) {
            int byte = ((nt * 16 + l15) * 256 + (ks * 32 + hi * 8) * 2) ^ ((l15 & 7) << 4);
            short8 bfr = *(const short8*)((const char*)bt + byte);
            acc[nt] = __builtin_amdgcn_mfma_f32_16x16x32_bf16(a[ks], bfr, acc[nt], 0, 0, 0);
        }
    }

    int rowbase = blockIdx.x * 64 + w * 16 + hi * 4;
    #pragma unroll
    for (int r = 0; r < 4; ++r) {
        int ro = rowbase + r;
        if (ro < NN) {
            float v[8];
            #pragma unroll
            for (int nt = 0; nt < 8; ++nt) {
                int col = nt * 16 + l15;
                v[nt] = fmaxf(acc[nt][r] + bl_s[col], 0.f);
                h0[ro * 128 + col] = f2bf(v[nt]);
            }
            // fp8 pack: bytes (col&15)*8 + (col>>4) -> this thread owns bytes l15*8 .. +7
            unsigned lo = 0, hiw = 0;
            lo  = __builtin_amdgcn_cvt_pk_fp8_f32(v[0], v[1], lo, false);
            lo  = __builtin_amdgcn_cvt_pk_fp8_f32(v[2], v[3], lo, true);
            hiw = __builtin_amdgcn_cvt_pk_fp8_f32(v[4], v[5], hiw, false);
            hiw = __builtin_amdgcn_cvt_pk_fp8_f32(v[6], v[7], hiw, true);
            uint2 q; q.x = lo; q.y = hiw;
            *(uint2*)(h8 + ro * 128 + l15 * 8) = q;
        }
    }
}

// ---------------- dense1 + fc fused (unchanged from R11) ----------------
__global__ __launch_bounds__(256) void dense1_k(
    const ushort* __restrict__ h0, const ushort* __restrict__ agg1,
    const ushort* __restrict__ wbt1, const float* __restrict__ bl,
    const float* __restrict__ Wfc, const float* __restrict__ bfc,
    float* __restrict__ out)
{
    __shared__ ushort bt[256 * 128];
    __shared__ float  bl_s[128];
    __shared__ float  wfc_s[256];

    #pragma unroll
    for (int c = 0; c < 16; ++c) {
        int i = threadIdx.x + c * 256;
        ((short8*)bt)[i] = ((const short8*)wbt1)[i];
    }
    if (threadIdx.x < 128) bl_s[threadIdx.x] = bl[threadIdx.x];
    if (threadIdx.x < 256) wfc_s[threadIdx.x] = Wfc[threadIdx.x];
    __syncthreads();

    int w = threadIdx.x >> 6, l = threadIdx.x & 63;
    int l15 = l & 15, hi = l >> 4;
    int row  = blockIdx.x * 64 + w * 16 + l15;
    int rowc = row < NN ? row : 0;

    short8 a[8];
    #pragma unroll
    for (int ks = 0; ks < 4; ++ks)
        a[ks] = *(const short8*)(agg1 + rowc * 128 + ks * 32 + hi * 8);
    #pragma unroll
    for (int ks = 0; ks < 4; ++ks)
        a[4 + ks] = *(const short8*)(h0 + rowc * 128 + ks * 32 + hi * 8);

    f32x4 acc[8];
    #pragma unroll
    for (int nt = 0; nt < 8; ++nt) acc[nt] = (f32x4){0.f, 0.f, 0.f, 0.f};

    #pragma unroll
    for (int ks = 0; ks < 8; ++ks) {
        #pragma unroll
        for (int nt = 0; nt < 8; ++nt) {
            int byte = ((nt * 16 + l15) * 512 + (ks * 32 + hi * 8) * 2) ^ ((l15 & 7) << 4);
            short8 bfr = *(const short8*)((const char*)bt + byte);
            acc[nt] = __builtin_amdgcn_mfma_f32_16x16x32_bf16(a[ks], bfr, acc[nt], 0, 0, 0);
        }
    }

    int rowbase = blockIdx.x * 64 + w * 16 + hi * 4;
    #pragma unroll
    for (int r = 0; r < 4; ++r) {
        float p0 = 0.f, p1 = 0.f;
        #pragma unroll
        for (int nt = 0; nt < 8; ++nt) {
            int col = nt * 16 + l15;
            float h1 = fmaxf(acc[nt][r] + bl_s[col], 0.f);
            p0 += h1 * wfc_s[col];
            p1 += h1 * wfc_s[128 + col];
        }
        p0 += __shfl_xor(p0, 1, 64); p0 += __shfl_xor(p0, 2, 64);
        p0 += __shfl_xor(p0, 4, 64); p0 += __shfl_xor(p0, 8, 64);
        p1 += __shfl_xor(p1, 1, 64); p1 += __shfl_xor(p1, 2, 64);
        p1 += __shfl_xor(p1, 4, 64); p1 += __shfl_xor(p1, 8, 64);
        int ro = rowbase + r;
        if (l15 == 0 && ro < NN) {
            float2 o; o.x = p0 + bfc[0]; o.y = p1 + bfc[1];
            *(float2*)(out + ro * 2) = o;
        }
    }
}

extern "C" void kernel_launch(void* const* d_in, const int* in_sizes, int n_in,
                              void* d_out, int out_size, void* d_ws, size_t ws_size,
                              hipStream_t stream)
{
    const float* x   = (const float*)d_in[0];
    const int*   ei  = (const int*)d_in[1];
    const float* Wl0 = (const float*)d_in[2];
    const float* bl0 = (const float*)d_in[3];
    const float* Wr0 = (const float*)d_in[4];
    const float* Wl1 = (const float*)d_in[5];
    const float* bl1 = (const float*)d_in[6];
    const float* Wr1 = (const float*)d_in[7];
    const float* Wfc = (const float*)d_in[8];
    const float* bfc = (const float*)d_in[9];
    float* out = (float*)d_out;

    const int* src = ei;
    const int* dst = ei + NE;

    // ws layout (bytes):
    //   deg    @ 0          (200,000)   <- memset
    //   rowptr @ 200,000    (200,004)
    //   rank   @ 400,004    (3,200,000)
    //   nbr    @ 3,600,004  (3,200,000)
    //   aggB   @ 6,800,016  (12,800,000)
    //   h0B    @ 19,600,016 (12,800,000)
    //   bsum   @ 32,400,016 (784)
    //   xb     @ 32,401,600 (6,400,000)
    //   wbt0   @ 38,801,600 (32,768)
    //   wbt1   @ 38,834,368 (65,536)
    //   h8     @ 38,899,904 (6,400,000)
    char*   ws     = (char*)d_ws;
    int*    deg    = (int*)(ws);
    int*    rowptr = (int*)(ws + 200000);
    int*    rank   = (int*)(ws + 400004);
    int*    nbr    = (int*)(ws + 3600004);
    ushort* aggB   = (ushort*)(ws + 6800016);
    ushort* h0B    = (ushort*)(ws + 19600016);
    int*    bsum   = (int*)(ws + 32400016);
    ushort* xb     = (ushort*)(ws + 32401600);
    ushort* wbt0   = (ushort*)(ws + 38801600);
    ushort* wbt1   = (ushort*)(ws + 38834368);
    unsigned char* h8 = (unsigned char*)(ws + 38899904);

    hipMemsetAsync(deg, 0, 200000, stream);

    count_k  <<<3125, 256, 0, stream>>>(dst, deg, rank, x, xb,
                                        Wl0, Wr0, Wl1, Wr1, wbt0, wbt1);
    partial_k<<<NB, 256, 0, stream>>>(deg, bsum);
    emit_k   <<<NB, 256, 0, stream>>>(deg, bsum, rowptr);
    fill_k   <<<3125, 256, 0, stream>>>(src, dst, rowptr, rank, nbr);

    gather0_k<<<1563, 256, 0, stream>>>(xb, rowptr, nbr, aggB);
    dense0_k <<<782, 256, 0, stream>>>(xb, aggB, wbt0, bl0, h0B, h8);
    gather1_k<<<3125, 256, 0, stream>>>(h8, rowptr, nbr, aggB);
    dense1_k <<<782, 256, 0, stream>>>(h0B, aggB, wbt1, bl1, Wfc, bfc, out);
}